// Round 6
// baseline (897.045 us; speedup 1.0000x reference)
//
#include <hip/hip_runtime.h>
#include <math.h>

#define LT     4096      // tokens = 16*16*16
#define CDIM   384       // model dim
#define DI     768       // inner dim
#define DS     16        // state dim
#define NBATCH 2
#define NCHK   64        // scan chunks
#define CHSZ   64        // steps per chunk
#define MROWS  (NBATCH*LT)   // 8192

using short8 = __attribute__((ext_vector_type(8))) short;
using f32x4  = __attribute__((ext_vector_type(4))) float;

// branch 0: forward, 1: backward (flip), 2: slice permutation
__device__ __forceinline__ int posmap(int branch, int t){
  if (branch == 0) return t;
  if (branch == 1) return LT - 1 - t;
  return ((t & 15) << 8) | (t >> 4);   // perm[t] = (t%16)*256 + t/16
}

// f32 -> bf16 (round-to-nearest-even)
__device__ __forceinline__ short f2bf(float f){
  union { float f; unsigned u; } v; v.f = f;
  unsigned r = (v.u + 0x7FFFu + ((v.u >> 16) & 1u)) >> 16;
  return (short)r;
}

__device__ __forceinline__ float softplusf(float x){
  return (x > 20.f) ? x : __logf(1.f + __expf(x));
}

// ---------------- LayerNorm: x[B,C,L] -> xn[B*L, C], coalesced both sides ----
#define LNPAD 69
__global__ __launch_bounds__(256) void ln_kernel(const float* __restrict__ x,
    const float* __restrict__ gam, const float* __restrict__ bet,
    float* __restrict__ xn)
{
  __shared__ float tile[64 * LNPAD];
  __shared__ float redS[16][16][4];
  __shared__ float redS2[16][16][4];
  __shared__ float muL[64], rsL[64];
  const int b  = blockIdx.y;
  const int l0 = blockIdx.x * 64;
  const int t  = threadIdx.x;
  const int g  = t >> 4, lf = t & 15;
  float s[4] = {0,0,0,0}, s2[4] = {0,0,0,0};
  for (int cc = 0; cc < 24; cc++){
    const int c = cc*16 + g;
    const float4 v = *(const float4*)&x[((size_t)b*CDIM + c)*LT + l0 + lf*4];
    s[0]+=v.x; s[1]+=v.y; s[2]+=v.z; s[3]+=v.w;
    s2[0]+=v.x*v.x; s2[1]+=v.y*v.y; s2[2]+=v.z*v.z; s2[3]+=v.w*v.w;
  }
#pragma unroll
  for (int j = 0; j < 4; j++){ redS[g][lf][j] = s[j]; redS2[g][lf][j] = s2[j]; }
  __syncthreads();
  if (t < 64){
    float ss = 0.f, ss2 = 0.f;
#pragma unroll
    for (int gg = 0; gg < 16; gg++){
      ss  += redS[gg][t>>2][t&3];
      ss2 += redS2[gg][t>>2][t&3];
    }
    const float mu  = ss * (1.f/CDIM);
    const float var = ss2 * (1.f/CDIM) - mu*mu;
    muL[t] = mu; rsL[t] = rsqrtf(var + 1e-5f);
  }
  __syncthreads();
  for (int chunk = 0; chunk < 6; chunk++){
    const int c0 = chunk*64;
#pragma unroll
    for (int p = 0; p < 4; p++){
      const int cl = p*16 + g;
      const float4 v = *(const float4*)&x[((size_t)b*CDIM + c0 + cl)*LT + l0 + lf*4];
      tile[cl*LNPAD + lf*4 + 0] = v.x;
      tile[cl*LNPAD + lf*4 + 1] = v.y;
      tile[cl*LNPAD + lf*4 + 2] = v.z;
      tile[cl*LNPAD + lf*4 + 3] = v.w;
    }
    __syncthreads();
    const int c_w = t & 63;
    const float gv = gam[c0 + c_w], bv = bet[c0 + c_w];
#pragma unroll
    for (int p = 0; p < 16; p++){
      const int l = p*4 + (t >> 6);
      xn[((size_t)b*LT + l0 + l)*CDIM + c0 + c_w] =
          (tile[c_w*LNPAD + l] - muL[l])*rsL[l]*gv + bv;
    }
    __syncthreads();
  }
}

// ---------------- MFMA NT GEMM: C[M,N] = (A ⊙ gateA)[M,K] * B[N,K]^T ---------
// act: 0 none, 2 relu, 3 silu, 4 split: n<DI -> C, n>=DI -> silu -> C2.
template<int WR, int WC, int MR, int NR>
__global__ __launch_bounds__(256) void gemm_mfma(const float* __restrict__ A, int lda,
    const float* __restrict__ gateA,
    const float* __restrict__ Bw, int ldb, const float* __restrict__ bias,
    float* __restrict__ C, float* __restrict__ C2,
    int ldc, int M, int N, int K, int act)
{
  constexpr int BM  = WR * MR * 16;
  constexpr int BN  = WC * NR * 16;
  constexpr int BKP = 40;                 // padded LDS row (shorts): 80 B
  __shared__ short As[BM * BKP];
  __shared__ short Bs[BN * BKP];
  const int tid  = threadIdx.x;
  const int m0   = blockIdx.x * BM;
  const int n0   = blockIdx.y * BN;
  const int w    = tid >> 6, lane = tid & 63;
  const int wm   = (w / WC) * MR * 16;
  const int wn   = (w % WC) * NR * 16;
  const int lrow = lane & 15;
  const int lko  = (lane >> 4) * 8;

  f32x4 acc[MR][NR];
#pragma unroll
  for (int i = 0; i < MR; i++)
#pragma unroll
    for (int j = 0; j < NR; j++) acc[i][j] = (f32x4){0.f, 0.f, 0.f, 0.f};

  const int srow = tid >> 3;              // 0..31
  const int skc  = (tid & 7) * 4;         // 0..28 step 4

  for (int k0 = 0; k0 < K; k0 += 32){
#pragma unroll
    for (int p = 0; p < BM/32; p++){
      const int r = p*32 + srow;
      const size_t gi = (size_t)(m0 + r)*lda + k0 + skc;
      float4 va = *(const float4*)&A[gi];
      if (gateA){
        float4 vg = *(const float4*)&gateA[gi];
        va.x *= vg.x; va.y *= vg.y; va.z *= vg.z; va.w *= vg.w;
      }
      short4 sv; sv.x = f2bf(va.x); sv.y = f2bf(va.y); sv.z = f2bf(va.z); sv.w = f2bf(va.w);
      *(short4*)&As[r*BKP + skc] = sv;
    }
#pragma unroll
    for (int p = 0; p < BN/32; p++){
      const int r = p*32 + srow;
      short4 sv; sv.x = sv.y = sv.z = sv.w = 0;
      if (n0 + r < N){
        const float4 vb = *(const float4*)&Bw[(size_t)(n0 + r)*ldb + k0 + skc];
        sv.x = f2bf(vb.x); sv.y = f2bf(vb.y); sv.z = f2bf(vb.z); sv.w = f2bf(vb.w);
      }
      *(short4*)&Bs[r*BKP + skc] = sv;
    }
    __syncthreads();
    short8 af[MR], bfr[NR];
#pragma unroll
    for (int mi = 0; mi < MR; mi++)
      af[mi] = *(const short8*)&As[(wm + mi*16 + lrow)*BKP + lko];
#pragma unroll
    for (int nj = 0; nj < NR; nj++)
      bfr[nj] = *(const short8*)&Bs[(wn + nj*16 + lrow)*BKP + lko];
#pragma unroll
    for (int mi = 0; mi < MR; mi++)
#pragma unroll
      for (int nj = 0; nj < NR; nj++)
        acc[mi][nj] = __builtin_amdgcn_mfma_f32_16x16x32_bf16(af[mi], bfr[nj],
                                                              acc[mi][nj], 0, 0, 0);
    __syncthreads();
  }
#pragma unroll
  for (int mi = 0; mi < MR; mi++){
#pragma unroll
    for (int nj = 0; nj < NR; nj++){
      const int n = n0 + wn + nj*16 + lrow;
      if (n >= N) continue;
      const float bv = bias ? bias[n] : 0.f;
#pragma unroll
      for (int reg = 0; reg < 4; reg++){
        const int m = m0 + wm + mi*16 + (lane >> 4)*4 + reg;
        float v = acc[mi][nj][reg] + bv;
        if (act == 2) v = fmaxf(v, 0.f);
        else if (act == 3) v = v / (1.f + __expf(-v));
        if (act == 4){
          if (n < DI) C[(size_t)m*DI + n] = v;
          else { C2[(size_t)m*DI + (n - DI)] = v / (1.f + __expf(-v)); }
        } else {
          C[(size_t)m*ldc + n] = v;
        }
      }
    }
  }
}

// ---------------- Depthwise causal conv1d(k=4) + SiLU, sliding window --------
__global__ __launch_bounds__(256) void conv_branch(const float* __restrict__ xi,
    const float* __restrict__ w, const float* __restrict__ bias,
    float* __restrict__ xc, int branch)
{
  const int d  = blockIdx.x*256 + threadIdx.x;
  const int t0 = blockIdx.y*4;
  const int b  = blockIdx.z;
  const float w0 = w[d*4+0], w1 = w[d*4+1], w2 = w[d*4+2], w3 = w[d*4+3];
  const float bv = bias[d];
  float xm3 = 0.f, xm2 = 0.f, xm1 = 0.f;
  if (t0 > 0){
    xm3 = xi[((size_t)b*LT + posmap(branch, t0-3))*DI + d];
    xm2 = xi[((size_t)b*LT + posmap(branch, t0-2))*DI + d];
    xm1 = xi[((size_t)b*LT + posmap(branch, t0-1))*DI + d];
  }
#pragma unroll
  for (int i = 0; i < 4; i++){
    const int t = t0 + i;
    const float cur = xi[((size_t)b*LT + posmap(branch, t))*DI + d];
    const float acc = bv + w0*xm3 + w1*xm2 + w2*xm1 + w3*cur;
    const float sg = 1.f / (1.f + __expf(-acc));
    xc[((size_t)b*LT + t)*DI + d] = acc * sg;
    xm3 = xm2; xm2 = xm1; xm1 = cur;
  }
}

// ===================== SCAN (state-quad lane split, LDS dtv table) ==========
// Block: 256 thr = 64 d-channels x 4 state-quads. Pre-pass computes
// dtv[t][d] once (6x ds_read_b128 dot24 + softplus), inner loop reads it
// broadcast. B/C fragments read as f32x4 (4 distinct addrs/wave).

// ---- phase A: local scan (h0=0) -> hfin, sdt --------------------------------
__global__ __launch_bounds__(256) void scan_hs(const float* __restrict__ xc,
    const float* __restrict__ dbl, const float* __restrict__ dtw,
    const float* __restrict__ dtb, const float* __restrict__ Alog,
    float* __restrict__ hfin, float* __restrict__ sdt_buf)
{
  __shared__ float bc[CHSZ*56];
  __shared__ float dtvS[CHSZ*64];
  const int t  = threadIdx.x;
  const int q  = t & 3;
  const int dl = t >> 2;
  const int d  = blockIdx.x*64 + dl;
  const int c  = blockIdx.y;
  const int b  = blockIdx.z;
  const size_t row0 = (size_t)b*LT + c*CHSZ;
  {
    const float4* src = (const float4*)(dbl + row0*56);
    float4* dst = (float4*)bc;
    for (int i = t; i < CHSZ*56/4; i += 256) dst[i] = src[i];
  }
  float wdt[24];
#pragma unroll
  for (int j = 0; j < 24; j++) wdt[j] = dtw[d*24 + j];
  const float bdt = dtb[d];
  float Ad[4];
#pragma unroll
  for (int j = 0; j < 4; j++) Ad[j] = -__expf(Alog[d*DS + q*4 + j]);
  __syncthreads();
  // dtv pre-pass: 16 rows per thread
#pragma unroll
  for (int i = 0; i < 16; i++){
    const int tl = q*16 + i;
    const float* r = bc + tl*56;
    float p = bdt;
#pragma unroll
    for (int j = 0; j < 24; j++) p += r[j]*wdt[j];
    dtvS[tl*64 + dl] = softplusf(p);
  }
  __syncthreads();
  float h[4] = {0.f,0.f,0.f,0.f};
  float sdt = 0.f;
  for (int tl = 0; tl < CHSZ; tl++){
    const float dtv = dtvS[tl*64 + dl];
    const float u = xc[(row0 + tl)*DI + d];
    const f32x4 Bv = *(const f32x4*)&bc[tl*56 + 24 + q*4];
    const float du = dtv * u;
#pragma unroll
    for (int j = 0; j < 4; j++)
      h[j] = h[j]*__expf(dtv*Ad[j]) + du*Bv[j];
    sdt += dtv;
  }
  const size_t off = ((size_t)b*NCHK + c)*DI + d;
  *(f32x4*)&hfin[off*DS + q*4] = (f32x4){h[0], h[1], h[2], h[3]};
  if (q == 0) sdt_buf[off] = sdt;
}

// ---- phase B: sequential carry over chunks, state-quad split ----------------
__global__ __launch_bounds__(256) void scan_b(const float* __restrict__ hfin,
    const float* __restrict__ sdt_buf, const float* __restrict__ Alog,
    float* __restrict__ carry)
{
  const int t = threadIdx.x;
  const int q = t & 3;
  const int d = blockIdx.x*64 + (t >> 2);
  const int b = blockIdx.y;
  float Ad[4];
#pragma unroll
  for (int j = 0; j < 4; j++) Ad[j] = -__expf(Alog[d*DS + q*4 + j]);
  float cr[4] = {0.f,0.f,0.f,0.f};
  for (int c = 0; c < NCHK; c++){
    const size_t off = ((size_t)b*NCHK + c)*DI + d;
    *(f32x4*)&carry[off*DS + q*4] = (f32x4){cr[0], cr[1], cr[2], cr[3]};
    const float sd = sdt_buf[off];
    const f32x4 hf = *(const f32x4*)&hfin[off*DS + q*4];
#pragma unroll
    for (int j = 0; j < 4; j++) cr[j] = hf[j] + __expf(Ad[j]*sd)*cr[j];
  }
}

// ---- phase C: rescan with h0=carry, write y ---------------------------------
__global__ __launch_bounds__(256) void scan_y(const float* __restrict__ xc,
    const float* __restrict__ dbl, const float* __restrict__ dtw,
    const float* __restrict__ dtb, const float* __restrict__ Alog,
    const float* __restrict__ Dp, const float* __restrict__ carry,
    float* __restrict__ y, int branch, int accum)
{
  __shared__ float bc[CHSZ*56];
  __shared__ float dtvS[CHSZ*64];
  const int t  = threadIdx.x;
  const int q  = t & 3;
  const int dl = t >> 2;
  const int d  = blockIdx.x*64 + dl;
  const int c  = blockIdx.y;
  const int b  = blockIdx.z;
  const size_t row0 = (size_t)b*LT + c*CHSZ;
  {
    const float4* src = (const float4*)(dbl + row0*56);
    float4* dst = (float4*)bc;
    for (int i = t; i < CHSZ*56/4; i += 256) dst[i] = src[i];
  }
  float wdt[24];
#pragma unroll
  for (int j = 0; j < 24; j++) wdt[j] = dtw[d*24 + j];
  const float bdt = dtb[d];
  float Ad[4];
#pragma unroll
  for (int j = 0; j < 4; j++) Ad[j] = -__expf(Alog[d*DS + q*4 + j]);
  const float Dpv = Dp[d];
  const size_t coff = (((size_t)b*NCHK + c)*DI + d)*DS;
  float h[4];
  {
    const f32x4 cv = *(const f32x4*)&carry[coff + q*4];
    h[0] = cv[0]; h[1] = cv[1]; h[2] = cv[2]; h[3] = cv[3];
  }
  __syncthreads();
#pragma unroll
  for (int i = 0; i < 16; i++){
    const int tl = q*16 + i;
    const float* r = bc + tl*56;
    float p = bdt;
#pragma unroll
    for (int j = 0; j < 24; j++) p += r[j]*wdt[j];
    dtvS[tl*64 + dl] = softplusf(p);
  }
  __syncthreads();
  for (int tl = 0; tl < CHSZ; tl++){
    const float dtv = dtvS[tl*64 + dl];
    const float u = xc[(row0 + tl)*DI + d];
    const f32x4 Bv = *(const f32x4*)&bc[tl*56 + 24 + q*4];
    const f32x4 Cv = *(const f32x4*)&bc[tl*56 + 40 + q*4];
    const float du = dtv * u;
    float yv = 0.f;
#pragma unroll
    for (int j = 0; j < 4; j++){
      h[j] = h[j]*__expf(dtv*Ad[j]) + du*Bv[j];
      yv  += h[j]*Cv[j];
    }
    yv += __shfl_xor(yv, 1);
    yv += __shfl_xor(yv, 2);
    if (q == 0){
      const float out = yv + u*Dpv;
      const size_t oidx = ((size_t)b*LT + posmap(branch, c*CHSZ + tl))*DI + d;
      if (accum) y[oidx] += out; else y[oidx] = out;
    }
  }
}

// ------- fused: osum = xsq + xsl, plus 128 partial sums for global pool ------
__global__ __launch_bounds__(384) void add_gp(const float* __restrict__ xsq,
    const float* __restrict__ xsl, float* __restrict__ osum,
    float* __restrict__ gpp)
{
  const int c = threadIdx.x;      // 384
  const int p = blockIdx.x;       // 128 partials
  const int b = blockIdx.y;
  const int l0 = p * (LT/128);    // 32 rows each
  float s = 0.f;
  for (int i = 0; i < LT/128; i++){
    const size_t idx = ((size_t)b*LT + l0 + i)*CDIM + c;
    const float v = xsq[idx] + xsl[idx];
    osum[idx] = v;
    s += v;
  }
  gpp[((size_t)b*128 + p)*CDIM + c] = s;
}

// ---------------- gf = relu(gp@c1w^T + c1b) @ c2w^T + c2b --------------------
__global__ __launch_bounds__(384) void gf_kernel(const float* __restrict__ gpp,
    const float* __restrict__ c1w, const float* __restrict__ c1b,
    const float* __restrict__ c2w, const float* __restrict__ c2b,
    float* __restrict__ gf)
{
  __shared__ float gpl[CDIM];
  __shared__ float t1[CDIM];
  const int b = blockIdx.x, o = threadIdx.x;
  float s = 0.f;
  for (int p = 0; p < 128; p++) s += gpp[((size_t)b*128 + p)*CDIM + o];
  gpl[o] = s * (1.f/LT);
  __syncthreads();
  float a = c1b[o];
  for (int c = 0; c < CDIM; c++) a += gpl[c]*c1w[o*CDIM + c];
  t1[o] = fmaxf(a, 0.f);
  __syncthreads();
  float g2 = c2b[o];
  for (int c = 0; c < CDIM; c++) g2 += t1[c]*c2w[o*CDIM + c];
  gf[b*CDIM + o] = g2;
}

// ---- final: wff=sigmoid(gf+sp2); out = xsq*wff+(1-wff)*xsl + x -> [B,C,L] ---
#define FTPAD 68
__global__ __launch_bounds__(256) void final_kernel(const float* __restrict__ xsq,
    const float* __restrict__ xsl, const float* __restrict__ sp2,
    const float* __restrict__ gf, const float* __restrict__ x,
    float* __restrict__ out)
{
  __shared__ float vt[64 * FTPAD];
  __shared__ float gfl[64];
  const int b  = blockIdx.z;
  const int c0 = blockIdx.y * 64;
  const int l0 = blockIdx.x * 64;
  const int t  = threadIdx.x;
  if (t < 64) gfl[t] = gf[b*CDIM + c0 + t];
  __syncthreads();
  const int lf = t & 15;
#pragma unroll
  for (int p = 0; p < 4; p++){
    const int ll = (t >> 4) + p*16;
    const size_t base = ((size_t)b*LT + l0 + ll)*CDIM + c0 + lf*4;
    const float4 a = *(const float4*)&xsq[base];
    const float4 s = *(const float4*)&xsl[base];
    const float4 c = *(const float4*)&sp2[base];
    float4 v;
    { const float wf = 1.f/(1.f+__expf(-(gfl[lf*4+0] + c.x))); v.x = a.x*wf + (1.f-wf)*s.x; }
    { const float wf = 1.f/(1.f+__expf(-(gfl[lf*4+1] + c.y))); v.y = a.y*wf + (1.f-wf)*s.y; }
    { const float wf = 1.f/(1.f+__expf(-(gfl[lf*4+2] + c.z))); v.z = a.z*wf + (1.f-wf)*s.z; }
    { const float wf = 1.f/(1.f+__expf(-(gfl[lf*4+3] + c.w))); v.w = a.w*wf + (1.f-wf)*s.w; }
    *(float4*)&vt[ll*FTPAD + lf*4] = v;
  }
  __syncthreads();
#pragma unroll
  for (int q = 0; q < 4; q++){
    const int c_w = (t >> 4) + q*16;
    const size_t oi = ((size_t)b*CDIM + c0 + c_w)*LT + l0 + lf*4;
    const float4 xv = *(const float4*)&x[oi];
    float4 o;
    o.x = vt[(lf*4+0)*FTPAD + c_w] + xv.x;
    o.y = vt[(lf*4+1)*FTPAD + c_w] + xv.y;
    o.z = vt[(lf*4+2)*FTPAD + c_w] + xv.z;
    o.w = vt[(lf*4+3)*FTPAD + c_w] + xv.w;
    *(float4*)&out[oi] = o;
  }
}

extern "C" void kernel_launch(void* const* d_in, const int* in_sizes, int n_in,
                              void* d_out, int out_size, void* d_ws, size_t ws_size,
                              hipStream_t stream)
{
  (void)in_sizes; (void)n_in; (void)out_size;
  const float* X    = (const float*)d_in[0];
  const float* LNG  = (const float*)d_in[1];
  const float* LNB  = (const float*)d_in[2];
  const float* INW  = (const float*)d_in[3];
  const float* OUTW = (const float*)d_in[4];
  const float *CONVW[3], *CONVB[3], *XPW[3], *DTW[3], *DTB[3], *ALOG[3], *DPP[3];
  for (int t = 0; t < 3; t++){
    int base = 5 + 7*t;
    CONVW[t] = (const float*)d_in[base + 0];
    CONVB[t] = (const float*)d_in[base + 1];
    XPW[t]   = (const float*)d_in[base + 2];
    DTW[t]   = (const float*)d_in[base + 3];
    DTB[t]   = (const float*)d_in[base + 4];
    ALOG[t]  = (const float*)d_in[base + 5];
    DPP[t]   = (const float*)d_in[base + 6];
  }
  const float* C1W = (const float*)d_in[26];
  const float* C1B = (const float*)d_in[27];
  const float* C2W = (const float*)d_in[28];
  const float* C2B = (const float*)d_in[29];
  const float* C3W = (const float*)d_in[30];
  const float* C3B = (const float*)d_in[31];
  const float* C4W = (const float*)d_in[32];
  const float* C4B = (const float*)d_in[33];

  // ---- workspace layout (f32 slots), total 32,014,336 f32 = 122.1 MiB ----
  const size_t SCR_SZ = 9994240;   // scratch region (aliased across phases)
  size_t off = 0;
  float* ws   = (float*)d_ws;
  float* SCR  = ws + off; off += SCR_SZ;
  float* XI   = ws + off; off += (size_t)MROWS*DI;     // 6,291,456
  float* GATE = ws + off; off += (size_t)MROWS*DI;     // 6,291,456
  float* Y    = ws + off; off += (size_t)MROWS*DI;     // 6,291,456
  float* XSL  = ws + off; off += (size_t)MROWS*CDIM;   // 3,145,728
  const size_t need_bytes = off * sizeof(float);
  if (ws_size < need_bytes) return;   // diagnostic: clean absmax-fail, not a fault

  // scratch aliases
  float* XN   = SCR;                                   // phase 1 (3,145,728)
  float* XC   = SCR;                                   // branch (6,291,456)
  float* DBLB = SCR + 6291456;                         // 458,752
  float* HFIN = SCR + 6750208;                         // 1,572,864
  float* SDT  = SCR + 8323072;                         // 98,304
  float* CARR = SCR + 8421376;                         // 1,572,864  (end 9,994,240)
  float* OSUM = SCR;                                   // fusion (3,145,728)
  float* SP1  = SCR + 3145728;                         // 3,145,728
  float* SP2  = SCR + 6291456;                         // 3,145,728
  float* GPP  = SCR + 9437184;                         // 98,304 (inside dead CARR)
  float* GF   = SCR + 9535488;                         // 768
  float* XSQ  = XI;   // XI region is dead after the last conv_branch
  float* DOUT = (float*)d_out;

  // 1) LayerNorm (tiled transpose)
  ln_kernel<<<dim3(LT/64, NBATCH), 256, 0, stream>>>(X, LNG, LNB, XN);
  // 2) fused in-proj: XI = xn @ in_w[0:768]^T ; GATE = silu(xn @ in_w[768:]^T)
  gemm_mfma<4,1,2,4><<<dim3(64, 24), 256, 0, stream>>>(XN, CDIM, nullptr,
      INW, CDIM, nullptr, XI, GATE, 0, MROWS, 2*DI, CDIM, 4);
  // 3) branches in order s(2), f(0), b(1): XSQ can then reuse XI space
  const int order[3] = {2, 0, 1};
  for (int oi_ = 0; oi_ < 3; oi_++){
    const int t = order[oi_];
    conv_branch<<<dim3(3, LT/4, NBATCH), 256, 0, stream>>>(XI, CONVW[t], CONVB[t], XC, t);
    gemm_mfma<2,2,2,2><<<dim3(128, 1), 256, 0, stream>>>(XC, DI, nullptr,
        XPW[t], DI, nullptr, DBLB, nullptr, 56, MROWS, 56, DI, 0);
    scan_hs<<<dim3(DI/64, NCHK, NBATCH), 256, 0, stream>>>(XC, DBLB, DTW[t], DTB[t],
                                                           ALOG[t], HFIN, SDT);
    scan_b<<<dim3(DI/64, NBATCH), 256, 0, stream>>>(HFIN, SDT, ALOG[t], CARR);
    scan_y<<<dim3(DI/64, NCHK, NBATCH), 256, 0, stream>>>(XC, DBLB, DTW[t], DTB[t],
                                                          ALOG[t], DPP[t], CARR, Y,
                                                          t, (t == 1) ? 1 : 0);
    if (t == 2){       // XSL = (Y ⊙ GATE) @ out_w^T  (token-major)
      gemm_mfma<4,1,2,4><<<dim3(64, 6), 256, 0, stream>>>(Y, DI, GATE,
          OUTW, DI, nullptr, XSL, nullptr, CDIM, MROWS, CDIM, DI, 0);
    } else if (t == 1){ // XSQ = (Y ⊙ GATE) @ out_w^T  (token-major, into XI)
      gemm_mfma<4,1,2,4><<<dim3(64, 6), 256, 0, stream>>>(Y, DI, GATE,
          OUTW, DI, nullptr, XSQ, nullptr, CDIM, MROWS, CDIM, DI, 0);
    }
  }
  // 4) fusion
  add_gp<<<dim3(128, NBATCH), 384, 0, stream>>>(XSQ, XSL, OSUM, GPP);
  gf_kernel<<<dim3(NBATCH), 384, 0, stream>>>(GPP, C1W, C1B, C2W, C2B, GF);
  gemm_mfma<4,1,2,4><<<dim3(64, 6), 256, 0, stream>>>(OSUM, CDIM, nullptr,
      C3W, CDIM, C3B, SP1, nullptr, CDIM, MROWS, CDIM, CDIM, 2);
  gemm_mfma<4,1,2,4><<<dim3(64, 6), 256, 0, stream>>>(SP1, CDIM, nullptr,
      C4W, CDIM, C4B, SP2, nullptr, CDIM, MROWS, CDIM, CDIM, 0);
  // 5) final gated combine + residual -> d_out [B,C,L] (tiled transpose)
  final_kernel<<<dim3(LT/64, CDIM/64, NBATCH), 256, 0, stream>>>(XSQ, XSL, SP2,
                                                                 GF, X, DOUT);
}

// Round 7
// 757.016 us; speedup vs baseline: 1.1850x; 1.1850x over previous
//
#include <hip/hip_runtime.h>
#include <math.h>

#define LT     4096      // tokens = 16*16*16
#define CDIM   384       // model dim
#define DI     768       // inner dim
#define DS     16        // state dim
#define NBATCH 2
#define NCHK   64        // scan chunks
#define CHSZ   64        // steps per chunk
#define MROWS  (NBATCH*LT)   // 8192

using short8 = __attribute__((ext_vector_type(8))) short;
using f32x4  = __attribute__((ext_vector_type(4))) float;

// branch 0: forward, 1: backward (flip), 2: slice permutation
__device__ __forceinline__ int posmap(int branch, int t){
  if (branch == 0) return t;
  if (branch == 1) return LT - 1 - t;
  return ((t & 15) << 8) | (t >> 4);   // perm[t] = (t%16)*256 + t/16
}

// f32 -> bf16 (round-to-nearest-even)
__device__ __forceinline__ short f2bf(float f){
  union { float f; unsigned u; } v; v.f = f;
  unsigned r = (v.u + 0x7FFFu + ((v.u >> 16) & 1u)) >> 16;
  return (short)r;
}
__device__ __forceinline__ float bf2f(short s){
  union { unsigned u; float f; } v; v.u = ((unsigned)(unsigned short)s) << 16;
  return v.f;
}

__device__ __forceinline__ float softplusf(float x){
  return (x > 20.f) ? x : __logf(1.f + __expf(x));
}

// ---------------- LayerNorm: x[B,C,L] -> xn[B*L, C], coalesced both sides ----
#define LNPAD 69
__global__ __launch_bounds__(256) void ln_kernel(const float* __restrict__ x,
    const float* __restrict__ gam, const float* __restrict__ bet,
    float* __restrict__ xn)
{
  __shared__ float tile[64 * LNPAD];
  __shared__ float redS[16][16][4];
  __shared__ float redS2[16][16][4];
  __shared__ float muL[64], rsL[64];
  const int b  = blockIdx.y;
  const int l0 = blockIdx.x * 64;
  const int t  = threadIdx.x;
  const int g  = t >> 4, lf = t & 15;
  float s[4] = {0,0,0,0}, s2[4] = {0,0,0,0};
  for (int cc = 0; cc < 24; cc++){
    const int c = cc*16 + g;
    const float4 v = *(const float4*)&x[((size_t)b*CDIM + c)*LT + l0 + lf*4];
    s[0]+=v.x; s[1]+=v.y; s[2]+=v.z; s[3]+=v.w;
    s2[0]+=v.x*v.x; s2[1]+=v.y*v.y; s2[2]+=v.z*v.z; s2[3]+=v.w*v.w;
  }
#pragma unroll
  for (int j = 0; j < 4; j++){ redS[g][lf][j] = s[j]; redS2[g][lf][j] = s2[j]; }
  __syncthreads();
  if (t < 64){
    float ss = 0.f, ss2 = 0.f;
#pragma unroll
    for (int gg = 0; gg < 16; gg++){
      ss  += redS[gg][t>>2][t&3];
      ss2 += redS2[gg][t>>2][t&3];
    }
    const float mu  = ss * (1.f/CDIM);
    const float var = ss2 * (1.f/CDIM) - mu*mu;
    muL[t] = mu; rsL[t] = rsqrtf(var + 1e-5f);
  }
  __syncthreads();
  for (int chunk = 0; chunk < 6; chunk++){
    const int c0 = chunk*64;
#pragma unroll
    for (int p = 0; p < 4; p++){
      const int cl = p*16 + g;
      const float4 v = *(const float4*)&x[((size_t)b*CDIM + c0 + cl)*LT + l0 + lf*4];
      tile[cl*LNPAD + lf*4 + 0] = v.x;
      tile[cl*LNPAD + lf*4 + 1] = v.y;
      tile[cl*LNPAD + lf*4 + 2] = v.z;
      tile[cl*LNPAD + lf*4 + 3] = v.w;
    }
    __syncthreads();
    const int c_w = t & 63;
    const float gv = gam[c0 + c_w], bv = bet[c0 + c_w];
#pragma unroll
    for (int p = 0; p < 16; p++){
      const int l = p*4 + (t >> 6);
      xn[((size_t)b*LT + l0 + l)*CDIM + c0 + c_w] =
          (tile[c_w*LNPAD + l] - muL[l])*rsL[l]*gv + bv;
    }
    __syncthreads();
  }
}

// ---------------- MFMA NT GEMM: C[M,N] = (A ⊙ gateA)[M,K] * B[N,K]^T ---------
// act: 0 none, 2 relu, 3 silu, 4 split(n<DI->C, else silu->C2),
//      5 softplus -> bf16 write (C treated as short*).
// Kact: valid K (cols >= Kact zero-padded; loads skipped -> no OOB).
template<int WR, int WC, int MR, int NR>
__global__ __launch_bounds__(256) void gemm_mfma(const float* __restrict__ A, int lda,
    const float* __restrict__ gateA,
    const float* __restrict__ Bw, int ldb, const float* __restrict__ bias,
    float* __restrict__ C, float* __restrict__ C2,
    int ldc, int M, int N, int K, int act, int Kact)
{
  constexpr int BM  = WR * MR * 16;
  constexpr int BN  = WC * NR * 16;
  constexpr int BKP = 40;                 // padded LDS row (shorts): 80 B
  __shared__ short As[BM * BKP];
  __shared__ short Bs[BN * BKP];
  const int tid  = threadIdx.x;
  const int m0   = blockIdx.x * BM;
  const int n0   = blockIdx.y * BN;
  const int w    = tid >> 6, lane = tid & 63;
  const int wm   = (w / WC) * MR * 16;
  const int wn   = (w % WC) * NR * 16;
  const int lrow = lane & 15;
  const int lko  = (lane >> 4) * 8;

  f32x4 acc[MR][NR];
#pragma unroll
  for (int i = 0; i < MR; i++)
#pragma unroll
    for (int j = 0; j < NR; j++) acc[i][j] = (f32x4){0.f, 0.f, 0.f, 0.f};

  const int srow = tid >> 3;              // 0..31
  const int skc  = (tid & 7) * 4;         // 0..28 step 4

  for (int k0 = 0; k0 < K; k0 += 32){
#pragma unroll
    for (int p = 0; p < BM/32; p++){
      const int r = p*32 + srow;
      short4 sv; sv.x = sv.y = sv.z = sv.w = 0;
      if (k0 + skc < Kact){
        const size_t gi = (size_t)(m0 + r)*lda + k0 + skc;
        float4 va = *(const float4*)&A[gi];
        if (gateA){
          float4 vg = *(const float4*)&gateA[gi];
          va.x *= vg.x; va.y *= vg.y; va.z *= vg.z; va.w *= vg.w;
        }
        sv.x = f2bf(va.x); sv.y = f2bf(va.y); sv.z = f2bf(va.z); sv.w = f2bf(va.w);
      }
      *(short4*)&As[r*BKP + skc] = sv;
    }
#pragma unroll
    for (int p = 0; p < BN/32; p++){
      const int r = p*32 + srow;
      short4 sv; sv.x = sv.y = sv.z = sv.w = 0;
      if (n0 + r < N && k0 + skc < Kact){
        const float4 vb = *(const float4*)&Bw[(size_t)(n0 + r)*ldb + k0 + skc];
        sv.x = f2bf(vb.x); sv.y = f2bf(vb.y); sv.z = f2bf(vb.z); sv.w = f2bf(vb.w);
      }
      *(short4*)&Bs[r*BKP + skc] = sv;
    }
    __syncthreads();
    short8 af[MR], bfr[NR];
#pragma unroll
    for (int mi = 0; mi < MR; mi++)
      af[mi] = *(const short8*)&As[(wm + mi*16 + lrow)*BKP + lko];
#pragma unroll
    for (int nj = 0; nj < NR; nj++)
      bfr[nj] = *(const short8*)&Bs[(wn + nj*16 + lrow)*BKP + lko];
#pragma unroll
    for (int mi = 0; mi < MR; mi++)
#pragma unroll
      for (int nj = 0; nj < NR; nj++)
        acc[mi][nj] = __builtin_amdgcn_mfma_f32_16x16x32_bf16(af[mi], bfr[nj],
                                                              acc[mi][nj], 0, 0, 0);
    __syncthreads();
  }
#pragma unroll
  for (int mi = 0; mi < MR; mi++){
#pragma unroll
    for (int nj = 0; nj < NR; nj++){
      const int n = n0 + wn + nj*16 + lrow;
      if (n >= N) continue;
      const float bv = bias ? bias[n] : 0.f;
#pragma unroll
      for (int reg = 0; reg < 4; reg++){
        const int m = m0 + wm + mi*16 + (lane >> 4)*4 + reg;
        float v = acc[mi][nj][reg] + bv;
        if (act == 2) v = fmaxf(v, 0.f);
        else if (act == 3) v = v / (1.f + __expf(-v));
        if (act == 4){
          if (n < DI) C[(size_t)m*DI + n] = v;
          else { C2[(size_t)m*DI + (n - DI)] = v / (1.f + __expf(-v)); }
        } else if (act == 5){
          ((short*)C)[(size_t)m*ldc + n] = f2bf(softplusf(v));
        } else {
          C[(size_t)m*ldc + n] = v;
        }
      }
    }
  }
}

// ---------------- Depthwise causal conv1d(k=4) + SiLU, sliding window --------
__global__ __launch_bounds__(256) void conv_branch(const float* __restrict__ xi,
    const float* __restrict__ w, const float* __restrict__ bias,
    float* __restrict__ xc, int branch)
{
  const int d  = blockIdx.x*256 + threadIdx.x;
  const int t0 = blockIdx.y*4;
  const int b  = blockIdx.z;
  const float w0 = w[d*4+0], w1 = w[d*4+1], w2 = w[d*4+2], w3 = w[d*4+3];
  const float bv = bias[d];
  float xm3 = 0.f, xm2 = 0.f, xm1 = 0.f;
  if (t0 > 0){
    xm3 = xi[((size_t)b*LT + posmap(branch, t0-3))*DI + d];
    xm2 = xi[((size_t)b*LT + posmap(branch, t0-2))*DI + d];
    xm1 = xi[((size_t)b*LT + posmap(branch, t0-1))*DI + d];
  }
#pragma unroll
  for (int i = 0; i < 4; i++){
    const int t = t0 + i;
    const float cur = xi[((size_t)b*LT + posmap(branch, t))*DI + d];
    const float acc = bv + w0*xm3 + w1*xm2 + w2*xm1 + w3*cur;
    const float sg = 1.f / (1.f + __expf(-acc));
    xc[((size_t)b*LT + t)*DI + d] = acc * sg;
    xm3 = xm2; xm2 = xm1; xm1 = cur;
  }
}

// ===================== SCAN (state-quad lane split, dtv from GEMM) ==========
// Block: 256 thr = 64 d-channels x 4 state-quads. dtv precomputed by the DT
// GEMM (bf16). LDS stages only the 32 B/C columns (8 KB).

// ---- phase A: local scan (h0=0) -> hfin, sdt --------------------------------
__global__ __launch_bounds__(256) void scan_hs(const float* __restrict__ xc,
    const float* __restrict__ dbl, const short* __restrict__ dtv_g,
    const float* __restrict__ Alog,
    float* __restrict__ hfin, float* __restrict__ sdt_buf)
{
  __shared__ float bc[CHSZ*32];
  const int t  = threadIdx.x;
  const int q  = t & 3;
  const int dl = t >> 2;
  const int d  = blockIdx.x*64 + dl;
  const int c  = blockIdx.y;
  const int b  = blockIdx.z;
  const size_t row0 = (size_t)b*LT + c*CHSZ;
  // stage B,C cols (24..55) of dbl rows row0..row0+63
  for (int i = t; i < CHSZ*8; i += 256){
    const int r = i >> 3, c4 = i & 7;
    *(float4*)&bc[r*32 + c4*4] = *(const float4*)&dbl[(row0 + r)*56 + 24 + c4*4];
  }
  float Ad[4];
#pragma unroll
  for (int j = 0; j < 4; j++) Ad[j] = -__expf(Alog[d*DS + q*4 + j]);
  __syncthreads();
  float h[4] = {0.f,0.f,0.f,0.f};
  float sdt = 0.f;
  for (int tl = 0; tl < CHSZ; tl++){
    const float dtv = bf2f(dtv_g[(row0 + tl)*DI + d]);
    const float u = xc[(row0 + tl)*DI + d];
    const f32x4 Bv = *(const f32x4*)&bc[tl*32 + q*4];
    const float du = dtv * u;
#pragma unroll
    for (int j = 0; j < 4; j++)
      h[j] = h[j]*__expf(dtv*Ad[j]) + du*Bv[j];
    sdt += dtv;
  }
  const size_t off = ((size_t)b*NCHK + c)*DI + d;
  *(f32x4*)&hfin[off*DS + q*4] = (f32x4){h[0], h[1], h[2], h[3]};
  if (q == 0) sdt_buf[off] = sdt;
}

// ---- phase B: sequential carry over chunks, IN PLACE over hfin --------------
__global__ __launch_bounds__(256) void scan_b(float* __restrict__ hfin,
    const float* __restrict__ sdt_buf, const float* __restrict__ Alog)
{
  const int t = threadIdx.x;
  const int q = t & 3;
  const int d = blockIdx.x*64 + (t >> 2);
  const int b = blockIdx.y;
  float Ad[4];
#pragma unroll
  for (int j = 0; j < 4; j++) Ad[j] = -__expf(Alog[d*DS + q*4 + j]);
  float cr[4] = {0.f,0.f,0.f,0.f};
  for (int c = 0; c < NCHK; c++){
    const size_t off = ((size_t)b*NCHK + c)*DI + d;
    const float sd = sdt_buf[off];
    const f32x4 hf = *(const f32x4*)&hfin[off*DS + q*4];
    *(f32x4*)&hfin[off*DS + q*4] = (f32x4){cr[0], cr[1], cr[2], cr[3]};
#pragma unroll
    for (int j = 0; j < 4; j++) cr[j] = hf[j] + __expf(Ad[j]*sd)*cr[j];
  }
}

// ---- phase C: rescan with h0=carry (in hfin), write y -----------------------
__global__ __launch_bounds__(256) void scan_y(const float* __restrict__ xc,
    const float* __restrict__ dbl, const short* __restrict__ dtv_g,
    const float* __restrict__ Alog, const float* __restrict__ Dp,
    const float* __restrict__ carry,
    float* __restrict__ y, int branch, int accum)
{
  __shared__ float bc[CHSZ*32];
  const int t  = threadIdx.x;
  const int q  = t & 3;
  const int dl = t >> 2;
  const int d  = blockIdx.x*64 + dl;
  const int c  = blockIdx.y;
  const int b  = blockIdx.z;
  const size_t row0 = (size_t)b*LT + c*CHSZ;
  for (int i = t; i < CHSZ*8; i += 256){
    const int r = i >> 3, c4 = i & 7;
    *(float4*)&bc[r*32 + c4*4] = *(const float4*)&dbl[(row0 + r)*56 + 24 + c4*4];
  }
  float Ad[4];
#pragma unroll
  for (int j = 0; j < 4; j++) Ad[j] = -__expf(Alog[d*DS + q*4 + j]);
  const float Dpv = Dp[d];
  const size_t coff = (((size_t)b*NCHK + c)*DI + d)*DS;
  float h[4];
  {
    const f32x4 cv = *(const f32x4*)&carry[coff + q*4];
    h[0] = cv[0]; h[1] = cv[1]; h[2] = cv[2]; h[3] = cv[3];
  }
  __syncthreads();
  for (int tl = 0; tl < CHSZ; tl++){
    const float dtv = bf2f(dtv_g[(row0 + tl)*DI + d]);
    const float u = xc[(row0 + tl)*DI + d];
    const f32x4 Bv = *(const f32x4*)&bc[tl*32 + q*4];
    const f32x4 Cv = *(const f32x4*)&bc[tl*32 + 16 + q*4];
    const float du = dtv * u;
    float yv = 0.f;
#pragma unroll
    for (int j = 0; j < 4; j++){
      h[j] = h[j]*__expf(dtv*Ad[j]) + du*Bv[j];
      yv  += h[j]*Cv[j];
    }
    yv += __shfl_xor(yv, 1);
    yv += __shfl_xor(yv, 2);
    if (q == 0){
      const float out = yv + u*Dpv;
      const size_t oidx = ((size_t)b*LT + posmap(branch, c*CHSZ + tl))*DI + d;
      if (accum) y[oidx] += out; else y[oidx] = out;
    }
  }
}

// ------- fused: osum = xsq + xsl, plus 128 partial sums for global pool ------
__global__ __launch_bounds__(384) void add_gp(const float* __restrict__ xsq,
    const float* __restrict__ xsl, float* __restrict__ osum,
    float* __restrict__ gpp)
{
  const int c = threadIdx.x;      // 384
  const int p = blockIdx.x;       // 128 partials
  const int b = blockIdx.y;
  const int l0 = p * (LT/128);    // 32 rows each
  float s = 0.f;
  for (int i = 0; i < LT/128; i++){
    const size_t idx = ((size_t)b*LT + l0 + i)*CDIM + c;
    const float v = xsq[idx] + xsl[idx];
    osum[idx] = v;
    s += v;
  }
  gpp[((size_t)b*128 + p)*CDIM + c] = s;
}

// ---------------- gf = relu(gp@c1w^T + c1b) @ c2w^T + c2b --------------------
__global__ __launch_bounds__(384) void gf_kernel(const float* __restrict__ gpp,
    const float* __restrict__ c1w, const float* __restrict__ c1b,
    const float* __restrict__ c2w, const float* __restrict__ c2b,
    float* __restrict__ gf)
{
  __shared__ float gpl[CDIM];
  __shared__ float t1[CDIM];
  const int b = blockIdx.x, o = threadIdx.x;
  float s = 0.f;
  for (int p = 0; p < 128; p++) s += gpp[((size_t)b*128 + p)*CDIM + o];
  gpl[o] = s * (1.f/LT);
  __syncthreads();
  float a = c1b[o];
  for (int c = 0; c < CDIM; c++) a += gpl[c]*c1w[o*CDIM + c];
  t1[o] = fmaxf(a, 0.f);
  __syncthreads();
  float g2 = c2b[o];
  for (int c = 0; c < CDIM; c++) g2 += t1[c]*c2w[o*CDIM + c];
  gf[b*CDIM + o] = g2;
}

// ---- final: wff=sigmoid(gf+sp2); out = xsq*wff+(1-wff)*xsl + x -> [B,C,L] ---
#define FTPAD 68
__global__ __launch_bounds__(256) void final_kernel(const float* __restrict__ xsq,
    const float* __restrict__ xsl, const float* __restrict__ sp2,
    const float* __restrict__ gf, const float* __restrict__ x,
    float* __restrict__ out)
{
  __shared__ float vt[64 * FTPAD];
  __shared__ float gfl[64];
  const int b  = blockIdx.z;
  const int c0 = blockIdx.y * 64;
  const int l0 = blockIdx.x * 64;
  const int t  = threadIdx.x;
  if (t < 64) gfl[t] = gf[b*CDIM + c0 + t];
  __syncthreads();
  const int lf = t & 15;
#pragma unroll
  for (int p = 0; p < 4; p++){
    const int ll = (t >> 4) + p*16;
    const size_t base = ((size_t)b*LT + l0 + ll)*CDIM + c0 + lf*4;
    const float4 a = *(const float4*)&xsq[base];
    const float4 s = *(const float4*)&xsl[base];
    const float4 c = *(const float4*)&sp2[base];
    float4 v;
    { const float wf = 1.f/(1.f+__expf(-(gfl[lf*4+0] + c.x))); v.x = a.x*wf + (1.f-wf)*s.x; }
    { const float wf = 1.f/(1.f+__expf(-(gfl[lf*4+1] + c.y))); v.y = a.y*wf + (1.f-wf)*s.y; }
    { const float wf = 1.f/(1.f+__expf(-(gfl[lf*4+2] + c.z))); v.z = a.z*wf + (1.f-wf)*s.z; }
    { const float wf = 1.f/(1.f+__expf(-(gfl[lf*4+3] + c.w))); v.w = a.w*wf + (1.f-wf)*s.w; }
    *(float4*)&vt[ll*FTPAD + lf*4] = v;
  }
  __syncthreads();
#pragma unroll
  for (int q = 0; q < 4; q++){
    const int c_w = (t >> 4) + q*16;
    const size_t oi = ((size_t)b*CDIM + c0 + c_w)*LT + l0 + lf*4;
    const float4 xv = *(const float4*)&x[oi];
    float4 o;
    o.x = vt[(lf*4+0)*FTPAD + c_w] + xv.x;
    o.y = vt[(lf*4+1)*FTPAD + c_w] + xv.y;
    o.z = vt[(lf*4+2)*FTPAD + c_w] + xv.z;
    o.w = vt[(lf*4+3)*FTPAD + c_w] + xv.w;
    *(float4*)&out[oi] = o;
  }
}

extern "C" void kernel_launch(void* const* d_in, const int* in_sizes, int n_in,
                              void* d_out, int out_size, void* d_ws, size_t ws_size,
                              hipStream_t stream)
{
  (void)in_sizes; (void)n_in; (void)out_size;
  const float* X    = (const float*)d_in[0];
  const float* LNG  = (const float*)d_in[1];
  const float* LNB  = (const float*)d_in[2];
  const float* INW  = (const float*)d_in[3];
  const float* OUTW = (const float*)d_in[4];
  const float *CONVW[3], *CONVB[3], *XPW[3], *DTW[3], *DTB[3], *ALOG[3], *DPP[3];
  for (int t = 0; t < 3; t++){
    int base = 5 + 7*t;
    CONVW[t] = (const float*)d_in[base + 0];
    CONVB[t] = (const float*)d_in[base + 1];
    XPW[t]   = (const float*)d_in[base + 2];
    DTW[t]   = (const float*)d_in[base + 3];
    DTB[t]   = (const float*)d_in[base + 4];
    ALOG[t]  = (const float*)d_in[base + 5];
    DPP[t]   = (const float*)d_in[base + 6];
  }
  const float* C1W = (const float*)d_in[26];
  const float* C1B = (const float*)d_in[27];
  const float* C2W = (const float*)d_in[28];
  const float* C2B = (const float*)d_in[29];
  const float* C3W = (const float*)d_in[30];
  const float* C3B = (const float*)d_in[31];
  const float* C4W = (const float*)d_in[32];
  const float* C4B = (const float*)d_in[33];

  // ---- workspace layout (f32 slots), total 32,014,336 f32 = 122.1 MiB ----
  const size_t SCR_SZ = 9994240;   // scratch region (aliased across phases)
  size_t off = 0;
  float* ws   = (float*)d_ws;
  float* SCR  = ws + off; off += SCR_SZ;
  float* XI   = ws + off; off += (size_t)MROWS*DI;     // 6,291,456
  float* GATE = ws + off; off += (size_t)MROWS*DI;     // 6,291,456
  float* Y    = ws + off; off += (size_t)MROWS*DI;     // 6,291,456
  float* XSL  = ws + off; off += (size_t)MROWS*CDIM;   // 3,145,728
  const size_t need_bytes = off * sizeof(float);
  if (ws_size < need_bytes) return;   // diagnostic: clean absmax-fail, not a fault

  // scratch aliases (branch phase):
  float* XN    = SCR;                                  // phase 1 (3,145,728)
  float* XC    = SCR;                                  // 6,291,456
  float* DBLB  = SCR + 6291456;                        // 458,752
  float* HFIN  = SCR + 6750208;                        // 1,572,864 (also carry)
  float* SDT   = SCR + 8323072;                        // 98,304
  short* DTBUF = (short*)(SCR + 8421376);              // MROWS*DI bf16 = 1,572,864 slots
  // fusion phase aliases:
  float* OSUM = SCR;                                   // 3,145,728
  float* SP1  = SCR + 3145728;                         // 3,145,728
  float* SP2  = SCR + 6291456;                         // 3,145,728
  float* GPP  = SCR + 8421376;                         // 98,304 (dead DT region)
  float* GF   = SCR + 8519680;                         // 768
  float* XSQ  = XI;   // XI region is dead after the last conv_branch
  float* DOUT = (float*)d_out;

  // 1) LayerNorm (tiled transpose)
  ln_kernel<<<dim3(LT/64, NBATCH), 256, 0, stream>>>(X, LNG, LNB, XN);
  // 2) fused in-proj: XI = xn @ in_w[0:768]^T ; GATE = silu(xn @ in_w[768:]^T)
  gemm_mfma<4,1,2,4><<<dim3(64, 24), 256, 0, stream>>>(XN, CDIM, nullptr,
      INW, CDIM, nullptr, XI, GATE, 0, MROWS, 2*DI, CDIM, 4, CDIM);
  // 3) branches in order s(2), f(0), b(1): XSQ can then reuse XI space
  const int order[3] = {2, 0, 1};
  for (int oi_ = 0; oi_ < 3; oi_++){
    const int t = order[oi_];
    conv_branch<<<dim3(3, LT/4, NBATCH), 256, 0, stream>>>(XI, CONVW[t], CONVB[t], XC, t);
    // x-proj: dbl[:,0:56] = xc @ xpw^T
    gemm_mfma<2,2,2,2><<<dim3(128, 1), 256, 0, stream>>>(XC, DI, nullptr,
        XPW[t], DI, nullptr, DBLB, nullptr, 56, MROWS, 56, DI, 0, DI);
    // dt GEMM: DTBUF = softplus(dbl[:,0:24] @ dtw^T + dtb)  (bf16 out)
    gemm_mfma<4,1,2,4><<<dim3(64, 12), 256, 0, stream>>>(DBLB, 56, nullptr,
        DTW[t], 24, DTB[t], (float*)DTBUF, nullptr, DI, MROWS, DI, 32, 5, 24);
    scan_hs<<<dim3(DI/64, NCHK, NBATCH), 256, 0, stream>>>(XC, DBLB, DTBUF,
                                                           ALOG[t], HFIN, SDT);
    scan_b<<<dim3(DI/64, NBATCH), 256, 0, stream>>>(HFIN, SDT, ALOG[t]);
    scan_y<<<dim3(DI/64, NCHK, NBATCH), 256, 0, stream>>>(XC, DBLB, DTBUF,
                                                          ALOG[t], DPP[t], HFIN, Y,
                                                          t, (t == 1) ? 1 : 0);
    if (t == 2){       // XSL = (Y ⊙ GATE) @ out_w^T  (token-major)
      gemm_mfma<4,1,2,4><<<dim3(64, 6), 256, 0, stream>>>(Y, DI, GATE,
          OUTW, DI, nullptr, XSL, nullptr, CDIM, MROWS, CDIM, DI, 0, DI);
    } else if (t == 1){ // XSQ = (Y ⊙ GATE) @ out_w^T  (token-major, into XI)
      gemm_mfma<4,1,2,4><<<dim3(64, 6), 256, 0, stream>>>(Y, DI, GATE,
          OUTW, DI, nullptr, XSQ, nullptr, CDIM, MROWS, CDIM, DI, 0, DI);
    }
  }
  // 4) fusion
  add_gp<<<dim3(128, NBATCH), 384, 0, stream>>>(XSQ, XSL, OSUM, GPP);
  gf_kernel<<<dim3(NBATCH), 384, 0, stream>>>(GPP, C1W, C1B, C2W, C2B, GF);
  gemm_mfma<4,1,2,4><<<dim3(64, 6), 256, 0, stream>>>(OSUM, CDIM, nullptr,
      C3W, CDIM, C3B, SP1, nullptr, CDIM, MROWS, CDIM, CDIM, 2, CDIM);
  gemm_mfma<4,1,2,4><<<dim3(64, 6), 256, 0, stream>>>(SP1, CDIM, nullptr,
      C4W, CDIM, C4B, SP2, nullptr, CDIM, MROWS, CDIM, CDIM, 0, CDIM);
  // 5) final gated combine + residual -> d_out [B,C,L] (tiled transpose)
  final_kernel<<<dim3(LT/64, CDIM/64, NBATCH), 256, 0, stream>>>(XSQ, XSL, SP2,
                                                                 GF, X, DOUT);
}